// Round 3
// baseline (195.230 us; speedup 1.0000x reference)
//
#include <hip/hip_runtime.h>
#include <hip/hip_bf16.h>
#include <math.h>

using bf16 = __hip_bfloat16;
typedef __attribute__((ext_vector_type(8))) short bf16x8;   // MFMA A/B frag
typedef __attribute__((ext_vector_type(4))) float f32x4;    // MFMA C/D frag
typedef __attribute__((ext_vector_type(4))) unsigned short us4;

#define GAS __attribute__((address_space(1)))
#define LAS __attribute__((address_space(3)))

__device__ __forceinline__ void gload_lds16(const bf16* g, bf16* lds) {
  __builtin_amdgcn_global_load_lds((const GAS void*)g, (LAS void*)lds, 16, 0, 0);
}

// ---------------- compaction (atomic-free, stable => deterministic) ----------------
__global__ __launch_bounds__(256) void hist_k(const int* __restrict__ lab,
                                              int* __restrict__ blockHist) {
  const int blk = blockIdx.x, t = threadIdx.x;
  const int lane = t & 63, w = t >> 6;
  const int d = lab[blk * 256 + t];
  __shared__ int wc[4][3];
#pragma unroll
  for (int dd = 0; dd < 3; ++dd) {
    unsigned long long m = __ballot(d == dd);
    if (lane == 0) wc[w][dd] = __popcll(m);
  }
  __syncthreads();
  if (t < 3) blockHist[blk * 3 + t] = wc[0][t] + wc[1][t] + wc[2][t] + wc[3][t];
}

__global__ __launch_bounds__(256) void scan_k(const int* __restrict__ blockHist,
                                              int* __restrict__ blockOff,
                                              int* __restrict__ meta) {
  __shared__ int h[64][3];
  __shared__ int tot[3];
  const int t = threadIdx.x;
  if (t < 192) h[t / 3][t % 3] = blockHist[t];
  __syncthreads();
  if (t < 3) {
    int s = 0;
    for (int b = 0; b < 64; ++b) { int v = h[b][t]; h[b][t] = s; s += v; }
    tot[t] = s;
    meta[t] = s;
  }
  __syncthreads();
  if (t == 0) { meta[4] = 0; meta[5] = tot[0]; meta[6] = tot[0] + tot[1]; }
  if (t < 192) {
    int b = t / 3, d = t % 3;
    int base = (d == 0) ? 0 : (d == 1 ? tot[0] : tot[0] + tot[1]);
    blockOff[t] = base + h[b][d];
  }
}

__global__ __launch_bounds__(256) void scatter2_k(const int* __restrict__ lab,
                                                  const int* __restrict__ blockOff,
                                                  int* __restrict__ perm) {
  const int blk = blockIdx.x, t = threadIdx.x;
  const int lane = t & 63, w = t >> 6;
  const int i = blk * 256 + t;
  const int d = lab[i];
  __shared__ int wc[4][3];
  unsigned long long mymask = 0;
#pragma unroll
  for (int dd = 0; dd < 3; ++dd) {
    unsigned long long m = __ballot(d == dd);
    if (lane == 0) wc[w][dd] = __popcll(m);
    if (dd == d) mymask = m;
  }
  __syncthreads();
  int woff = 0;
  for (int ww = 0; ww < w; ++ww) woff += wc[ww][d];
  const unsigned long long lt = ((unsigned long long)1 << lane) - 1;
  const int rank = blockOff[blk * 3 + d] + woff + __popcll(mymask & lt);
  perm[rank] = i;
}

// ---------------- dtype conversions ----------------
__global__ __launch_bounds__(256) void cvt_bf16_k(const float* __restrict__ in,
                                                  bf16* __restrict__ out, int n4) {
  int i = blockIdx.x * 256 + threadIdx.x;
  if (i >= n4) return;
  float4 v = ((const float4*)in)[i];
  bf16 t[4] = {__float2bfloat16(v.x), __float2bfloat16(v.y),
               __float2bfloat16(v.z), __float2bfloat16(v.w)};
  ((us4*)out)[i] = *(const us4*)t;
}

// text (1380x1024) -> bf16 padded to 1536 rows (pad zero)
__global__ __launch_bounds__(256) void cvt_text_k(const float* __restrict__ in,
                                                  bf16* __restrict__ out) {
  int i = blockIdx.x * 256 + threadIdx.x;          // over 1536*1024/4
  const int n4v = 1380 * 1024 / 4;
  if (i >= 1536 * 1024 / 4) return;
  if (i < n4v) {
    float4 v = ((const float4*)in)[i];
    bf16 t[4] = {__float2bfloat16(v.x), __float2bfloat16(v.y),
                 __float2bfloat16(v.z), __float2bfloat16(v.w)};
    ((us4*)out)[i] = *(const us4*)t;
  } else {
    us4 z = {0, 0, 0, 0};
    ((us4*)out)[i] = z;
  }
}

__global__ __launch_bounds__(256) void cvt_w1t_k(const float* __restrict__ W1,
                                                 bf16* __restrict__ W1T) {
  int i = blockIdx.x * 256 + threadIdx.x;
  if (i >= 3 * 256 * 1024) return;
  int d = i >> 18, rem = i & 262143;
  int r = rem >> 10, k = rem & 1023;
  W1T[i] = __float2bfloat16(W1[(size_t)d * 262144 + (size_t)k * 256 + r]);
}
__global__ __launch_bounds__(256) void cvt_w2t_k(const float* __restrict__ W2,
                                                 bf16* __restrict__ W2T) {
  int i = blockIdx.x * 256 + threadIdx.x;
  if (i >= 3 * 1024 * 256) return;
  int d = i >> 18, rem = i & 262143;
  int n = rem >> 8, k = rem & 255;
  W2T[i] = __float2bfloat16(W2[(size_t)d * 262144 + (size_t)k * 1024 + n]);
}

// ---------------- 128^2 2-phase GEMM (verified) for GEMM1/GEMM2 ----------------
template <bool SEG, bool GATHER_A, bool SCATTER_C, bool RELU, bool C_BF16, bool SCALE>
__global__ __launch_bounds__(256) void gemm_bt(
    const bf16* __restrict__ A, const bf16* __restrict__ BT, void* __restrict__ Cv,
    const int* __restrict__ perm, const int* __restrict__ meta, int Mfull, int N,
    int K, int ldc, int Nvalid, const float* __restrict__ scale_ptr) {
  int cnt = Mfull, base = 0;
  if (SEG) {
    int dom = blockIdx.z;
    cnt = meta[dom];
    base = meta[4 + dom];
    BT += (size_t)dom * N * K;
  }
  const int m0 = blockIdx.x * 128;
  if (m0 >= cnt) return;
  const int n0 = blockIdx.y * 128;

  __shared__ bf16 sA[2][128][32];
  __shared__ bf16 sB[2][128][32];

  const int tid = threadIdx.x;
  const int wid = tid >> 6;
  const int lane = tid & 63;

  const int srow = (wid << 4) + (lane >> 2);
  const int skoff = (lane & 3) << 3;

  int p0 = m0 + srow;       if (p0 > cnt - 1) p0 = cnt - 1;
  int p1 = m0 + srow + 64;  if (p1 > cnt - 1) p1 = cnt - 1;
  long ar0, ar1;
  if (GATHER_A) { ar0 = perm[base + p0]; ar1 = perm[base + p1]; }
  else          { ar0 = base + p0;       ar1 = base + p1; }
  const bf16* a0 = A + (size_t)ar0 * K + skoff;
  const bf16* a1 = A + (size_t)ar1 * K + skoff;
  const bf16* b0 = BT + (size_t)(n0 + srow) * K + skoff;
  const bf16* b1 = BT + (size_t)(n0 + srow + 64) * K + skoff;

  const int fr = lane & 15;
  const int fq = lane >> 4;

  f32x4 acc[4][4];
#pragma unroll
  for (int m = 0; m < 4; ++m)
#pragma unroll
    for (int n = 0; n < 4; ++n) acc[m][n] = (f32x4){0.f, 0.f, 0.f, 0.f};

  const int nk = K >> 5;
  auto stage = [&](int buf, int kt) {
    gload_lds16(a0 + kt * 32, &sA[buf][wid * 16][0]);
    gload_lds16(a1 + kt * 32, &sA[buf][wid * 16 + 64][0]);
    gload_lds16(b0 + kt * 32, &sB[buf][wid * 16][0]);
    gload_lds16(b1 + kt * 32, &sB[buf][wid * 16 + 64][0]);
  };

  stage(0, 0);
  __syncthreads();
  const int wr = wid >> 1, wc = wid & 1;
  for (int kt = 0; kt < nk; ++kt) {
    const int cur = kt & 1;
    if (kt + 1 < nk) stage(cur ^ 1, kt + 1);
    bf16x8 af[4], bfr[4];
#pragma unroll
    for (int m = 0; m < 4; ++m)
      af[m] = *(const bf16x8*)&sA[cur][wr * 64 + m * 16 + fr][fq * 8];
#pragma unroll
    for (int n = 0; n < 4; ++n)
      bfr[n] = *(const bf16x8*)&sB[cur][wc * 64 + n * 16 + fr][fq * 8];
#pragma unroll
    for (int m = 0; m < 4; ++m)
#pragma unroll
      for (int n = 0; n < 4; ++n)
        acc[m][n] = __builtin_amdgcn_mfma_f32_16x16x32_bf16(af[m], bfr[n], acc[m][n], 0, 0, 0);
    __syncthreads();
  }

  float s = 1.f;
  if (SCALE) s = expf(*scale_ptr);
#pragma unroll
  for (int m = 0; m < 4; ++m) {
#pragma unroll
    for (int r = 0; r < 4; ++r) {
      const int p = m0 + wr * 64 + m * 16 + fq * 4 + r;
      if (p < cnt) {
        size_t crow;
        if (SCATTER_C) crow = perm[base + p];
        else if (SEG)  crow = base + p;
        else           crow = p;
#pragma unroll
        for (int n = 0; n < 4; ++n) {
          const int col = n0 + wc * 64 + n * 16 + fr;
          if (col < Nvalid) {
            float v = acc[m][n][r];
            if (RELU) v = fmaxf(v, 0.f);
            v *= s;
            if (C_BF16) ((bf16*)Cv)[crow * (size_t)ldc + col] = __float2bfloat16(v);
            else        ((float*)Cv)[crow * (size_t)ldc + col] = v;
          }
        }
      }
    }
  }
}

// ---------------- GEMM3: 256^2 tile, BK=64, 8 waves, counted-vmcnt pipeline ----------------
// C[16384][1380] = exp(ls) * A[16384][1024] @ BT[1536][1024]^T    (BT rows >=1380 zero-padded)
// LDS: 2 slots x (A 32KB + B 32KB) = 128 KB (dynamic). T2 chunk-XOR swizzle both-sides.
// Schedule per K-tile (4 phases, 16 MFMA each):
//  ph1: ds_read a0,b0(kk0) | stage (kt+1).Bh0 -> slot^1 | bar | MFMA kk0 n0-1 | bar
//  ph2:                      stage (kt+1).Bh1 -> slot^1 | bar | MFMA kk0 n2-3 | bar
//  ph3: ds_read a1,b1(kk1)                              | bar | MFMA kk1 n0-1 | bar
//  ph4: stage (kt+2).Ah0,Ah1 -> slot | vmcnt(4)         | bar | MFMA kk1 n2-3 | bar
// Stage->slot hazard: slot reads complete by ph3's MFMA (lgkm) + ph3-end barrier => ph4 stage safe.
// vmcnt(4) leaves only the 2 just-issued halves outstanding => tile kt+1 fully landed.
__global__ __launch_bounds__(512, 2) void gemm3_256(
    const bf16* __restrict__ A, const bf16* __restrict__ BT,
    float* __restrict__ C, const float* __restrict__ scale_ptr) {
  extern __shared__ bf16 smem[];
  bf16* sA0 = smem;            // [2][16384]
  bf16* sB0 = smem + 32768;    // [2][16384]

  const int tid = threadIdx.x;
  const int lane = tid & 63, wid = tid >> 6;
  const int wr = wid >> 2, wc = wid & 3;       // 2x4 wave grid; wave C = 128x64
  const int fr = lane & 15, fq = lane >> 4;

  // XCD-aware swizzle: 384 wgs, 384 % 8 == 0 -> bijective
  const int bid = blockIdx.x;
  const int wg = (bid & 7) * 48 + (bid >> 3);
  const int mb = wg & 63, nb = wg >> 6;        // nb-major within XCD chunk: share B panel
  const int m0 = mb << 8, n0 = nb << 8;

  // stage one half (u: 0=Ah0 1=Ah1 2=Bh0 3=Bh1) of tile kt; 2 x gload_lds16/thread.
  // Global source pre-swizzled: chunk c_phys at row r takes logical chunk c_phys^(r&7).
  auto STAGE = [&](int kt, int u) {
    const bf16* G = (u < 2) ? A : BT;
    const int row0 = ((u < 2) ? m0 : n0) + ((u & 1) << 7);
    bf16* dstb = ((u < 2) ? sA0 : sB0) + ((kt & 1) << 14) + ((u & 1) << 13);
    const int koff = kt << 6;
#pragma unroll
    for (int L = 0; L < 2; ++L) {
      const int idx = (L << 9) + tid;
      const int r = idx >> 3, c = idx & 7;
      gload_lds16(G + (size_t)(row0 + r) * 1024 + koff + ((c ^ (r & 7)) << 3),
                  dstb + ((idx & ~63) << 3));
    }
  };
  // frag reads with matching XOR: logical chunk (kk*4+fq) at row -> physical ^ (fr&7)
  auto LDA = [&](int slot, int kk, bf16x8* dst) {
    const bf16* base = sA0 + (slot << 14);
#pragma unroll
    for (int m = 0; m < 8; ++m) {
      const int row = (wr << 7) + (m << 4) + fr;
      dst[m] = *(const bf16x8*)(base + (row << 6) + ((((kk << 2) + fq) ^ (fr & 7)) << 3));
    }
  };
  auto LDB = [&](int slot, int kk, bf16x8* dst) {
    const bf16* base = sB0 + (slot << 14);
#pragma unroll
    for (int n = 0; n < 4; ++n) {
      const int row = (wc << 6) + (n << 4) + fr;
      dst[n] = *(const bf16x8*)(base + (row << 6) + ((((kk << 2) + fq) ^ (fr & 7)) << 3));
    }
  };

  f32x4 acc[8][4];
#pragma unroll
  for (int m = 0; m < 8; ++m)
#pragma unroll
    for (int n = 0; n < 4; ++n) acc[m][n] = (f32x4){0.f, 0.f, 0.f, 0.f};

#define SB __builtin_amdgcn_sched_barrier(0)
#define BAR __builtin_amdgcn_s_barrier()
#define MM2(AF, BF, N0)                                                                   \
  _Pragma("unroll") for (int m = 0; m < 8; ++m) {                                         \
    acc[m][N0]     = __builtin_amdgcn_mfma_f32_16x16x32_bf16(AF[m], BF[N0],     acc[m][N0],     0, 0, 0); \
    acc[m][N0 + 1] = __builtin_amdgcn_mfma_f32_16x16x32_bf16(AF[m], BF[N0 + 1], acc[m][N0 + 1], 0, 0, 0); \
  }

  // prologue: tile0 all 4 halves + tile1 A-halves; wait tile0 (4 loads may stay in flight)
  STAGE(0, 0); STAGE(0, 1); STAGE(0, 2); STAGE(0, 3);
  STAGE(1, 0); STAGE(1, 1);
  asm volatile("s_waitcnt vmcnt(4)" ::: "memory");
  SB; BAR; SB;

  const int nt = 16;
  for (int kt = 0; kt < nt; ++kt) {
    const int slot = kt & 1;
    bf16x8 a0[8], b0[4], a1[8], b1[4];
    // ---- ph1
    LDA(slot, 0, a0); LDB(slot, 0, b0);
    if (kt + 1 < nt) STAGE(kt + 1, 2);
    SB; BAR; SB;
    __builtin_amdgcn_s_setprio(1);
    MM2(a0, b0, 0);
    __builtin_amdgcn_s_setprio(0);
    SB; BAR; SB;
    // ---- ph2
    if (kt + 1 < nt) STAGE(kt + 1, 3);
    SB; BAR; SB;
    __builtin_amdgcn_s_setprio(1);
    MM2(a0, b0, 2);
    __builtin_amdgcn_s_setprio(0);
    SB; BAR; SB;
    // ---- ph3
    LDA(slot, 1, a1); LDB(slot, 1, b1);
    SB; BAR; SB;
    __builtin_amdgcn_s_setprio(1);
    MM2(a1, b1, 0);
    __builtin_amdgcn_s_setprio(0);
    SB; BAR; SB;
    // ---- ph4
    if (kt + 2 < nt) {
      STAGE(kt + 2, 0); STAGE(kt + 2, 1);
      asm volatile("s_waitcnt vmcnt(4)" ::: "memory");
    } else if (kt + 1 < nt) {
      asm volatile("s_waitcnt vmcnt(0)" ::: "memory");
    }
    SB; BAR; SB;
    __builtin_amdgcn_s_setprio(1);
    MM2(a1, b1, 2);
    __builtin_amdgcn_s_setprio(0);
    SB; BAR; SB;
  }
#undef MM2
#undef BAR
#undef SB

  const float sc = expf(*scale_ptr);
#pragma unroll
  for (int m = 0; m < 8; ++m) {
    const int grow = m0 + (wr << 7) + (m << 4) + (fq << 2);
#pragma unroll
    for (int r = 0; r < 4; ++r) {
#pragma unroll
      for (int n = 0; n < 4; ++n) {
        const int gcol = n0 + (wc << 6) + (n << 4) + fr;
        if (gcol < 1380) C[(size_t)(grow + r) * 1380 + gcol] = acc[m][n][r] * sc;
      }
    }
  }
}

// ---------------- fused = normalize(0.2*a + 0.8*x), in place over a (bf16) ----------------
__global__ __launch_bounds__(256) void fuse_norm_k(const float* __restrict__ x,
                                                   bf16* __restrict__ F) {
  const int row = blockIdx.x;
  const int t = threadIdx.x;
  const size_t roff = (size_t)row * 1024;
  float f[4];
  float ss = 0.f;
#pragma unroll
  for (int j = 0; j < 4; ++j) {
    const int c = t + j * 256;
    float a = __bfloat162float(F[roff + c]);
    float xv = x[roff + c];
    f[j] = 0.2f * a + 0.8f * xv;
    ss += f[j] * f[j];
  }
#pragma unroll
  for (int o = 32; o > 0; o >>= 1) ss += __shfl_down(ss, o);
  __shared__ float sred[4];
  if ((t & 63) == 0) sred[t >> 6] = ss;
  __syncthreads();
  const float rinv = 1.0f / sqrtf(sred[0] + sred[1] + sred[2] + sred[3]);
#pragma unroll
  for (int j = 0; j < 4; ++j) {
    const int c = t + j * 256;
    F[roff + c] = __float2bfloat16(f[j] * rinv);
  }
}

extern "C" void kernel_launch(void* const* d_in, const int* in_sizes, int n_in,
                              void* d_out, int out_size, void* d_ws, size_t ws_size,
                              hipStream_t stream) {
  (void)in_sizes; (void)n_in; (void)out_size; (void)ws_size;
  const float* x    = (const float*)d_in[0];
  const int*   lab  = (const int*)d_in[1];
  const float* W1   = (const float*)d_in[2];
  const float* W2   = (const float*)d_in[3];
  const float* text = (const float*)d_in[4];
  const float* lsc  = (const float*)d_in[5];
  float* out = (float*)d_out;

  const int B = 16384, D = 1024, R = 256, NTP = 1536;

  char* p = (char*)d_ws;
  auto carve = [&](size_t bytes) {
    char* r = p;
    p += (bytes + 255) & ~(size_t)255;
    return r;
  };
  int*  meta  = (int*)carve(64);
  int*  bhist = (int*)carve(64 * 3 * 4);
  int*  boff  = (int*)carve(64 * 3 * 4);
  int*  perm  = (int*)carve((size_t)B * 4);
  bf16* Xb    = (bf16*)carve((size_t)B * D * 2);     // reused as Fb after GEMM1
  bf16* W1T   = (bf16*)carve((size_t)3 * R * D * 2);
  bf16* W2T   = (bf16*)carve((size_t)3 * D * R * 2);
  bf16* Tb    = (bf16*)carve((size_t)NTP * D * 2);
  bf16* H     = (bf16*)carve((size_t)B * R * 2);
  bf16* Fb    = Xb;

  hist_k<<<B / 256, 256, 0, stream>>>(lab, bhist);
  scan_k<<<1, 256, 0, stream>>>(bhist, boff, meta);
  scatter2_k<<<B / 256, 256, 0, stream>>>(lab, boff, perm);

  cvt_bf16_k<<<(B * D / 4 + 255) / 256, 256, 0, stream>>>(x, Xb, B * D / 4);
  cvt_w1t_k<<<(3 * R * D + 255) / 256, 256, 0, stream>>>(W1, W1T);
  cvt_w2t_k<<<(3 * R * D + 255) / 256, 256, 0, stream>>>(W2, W2T);
  cvt_text_k<<<(NTP * D / 4 + 255) / 256, 256, 0, stream>>>(text, Tb);

  // GEMM1: H = relu(Xb[perm] @ W1T[dom]^T)   M=cnt N=256 K=1024
  dim3 g1(128, 2, 3);
  gemm_bt<true, true, false, true, true, false><<<g1, 256, 0, stream>>>(
      Xb, W1T, H, perm, meta, B, R, D, R, R, nullptr);
  // GEMM2: Fb[orig] = relu(H @ W2T[dom]^T)   M=cnt N=1024 K=256 (scatter)
  dim3 g2(128, 8, 3);
  gemm_bt<true, false, true, true, true, false><<<g2, 256, 0, stream>>>(
      H, W2T, Fb, perm, meta, B, D, R, D, D, nullptr);
  fuse_norm_k<<<B, 256, 0, stream>>>(x, Fb);
  // GEMM3: out = exp(ls) * Fb @ Tb^T   M=16384 N=1536(valid 1380) K=1024, 256^2 pipeline
  gemm3_256<<<384, 512, 131072, stream>>>(Fb, Tb, out, lsc);
}

// Round 4
// 188.868 us; speedup vs baseline: 1.0337x; 1.0337x over previous
//
#include <hip/hip_runtime.h>
#include <hip/hip_bf16.h>
#include <math.h>

using bf16 = __hip_bfloat16;
typedef __attribute__((ext_vector_type(8))) short bf16x8;   // MFMA A/B frag
typedef __attribute__((ext_vector_type(4))) float f32x4;    // MFMA C/D frag
typedef __attribute__((ext_vector_type(4))) unsigned short us4;

#define GAS __attribute__((address_space(1)))
#define LAS __attribute__((address_space(3)))

__device__ __forceinline__ void gload_lds16(const bf16* g, bf16* lds) {
  __builtin_amdgcn_global_load_lds((const GAS void*)g, (LAS void*)lds, 16, 0, 0);
}

// ---------------- compaction (atomic-free, stable => deterministic) ----------------
__global__ __launch_bounds__(256) void hist_k(const int* __restrict__ lab,
                                              int* __restrict__ blockHist) {
  const int blk = blockIdx.x, t = threadIdx.x;
  const int lane = t & 63, w = t >> 6;
  const int d = lab[blk * 256 + t];
  __shared__ int wc[4][3];
#pragma unroll
  for (int dd = 0; dd < 3; ++dd) {
    unsigned long long m = __ballot(d == dd);
    if (lane == 0) wc[w][dd] = __popcll(m);
  }
  __syncthreads();
  if (t < 3) blockHist[blk * 3 + t] = wc[0][t] + wc[1][t] + wc[2][t] + wc[3][t];
}

__global__ __launch_bounds__(256) void scan_k(const int* __restrict__ blockHist,
                                              int* __restrict__ blockOff,
                                              int* __restrict__ meta) {
  __shared__ int h[64][3];
  __shared__ int tot[3];
  const int t = threadIdx.x;
  if (t < 192) h[t / 3][t % 3] = blockHist[t];
  __syncthreads();
  if (t < 3) {
    int s = 0;
    for (int b = 0; b < 64; ++b) { int v = h[b][t]; h[b][t] = s; s += v; }
    tot[t] = s;
    meta[t] = s;
  }
  __syncthreads();
  if (t == 0) { meta[4] = 0; meta[5] = tot[0]; meta[6] = tot[0] + tot[1]; }
  if (t < 192) {
    int b = t / 3, d = t % 3;
    int base = (d == 0) ? 0 : (d == 1 ? tot[0] : tot[0] + tot[1]);
    blockOff[t] = base + h[b][d];
  }
}

__global__ __launch_bounds__(256) void scatter2_k(const int* __restrict__ lab,
                                                  const int* __restrict__ blockOff,
                                                  int* __restrict__ perm) {
  const int blk = blockIdx.x, t = threadIdx.x;
  const int lane = t & 63, w = t >> 6;
  const int i = blk * 256 + t;
  const int d = lab[i];
  __shared__ int wc[4][3];
  unsigned long long mymask = 0;
#pragma unroll
  for (int dd = 0; dd < 3; ++dd) {
    unsigned long long m = __ballot(d == dd);
    if (lane == 0) wc[w][dd] = __popcll(m);
    if (dd == d) mymask = m;
  }
  __syncthreads();
  int woff = 0;
  for (int ww = 0; ww < w; ++ww) woff += wc[ww][d];
  const unsigned long long lt = ((unsigned long long)1 << lane) - 1;
  const int rank = blockOff[blk * 3 + d] + woff + __popcll(mymask & lt);
  perm[rank] = i;
}

// ---------------- dtype conversions ----------------
__global__ __launch_bounds__(256) void cvt_bf16_k(const float* __restrict__ in,
                                                  bf16* __restrict__ out, int n4) {
  int i = blockIdx.x * 256 + threadIdx.x;
  if (i >= n4) return;
  float4 v = ((const float4*)in)[i];
  bf16 t[4] = {__float2bfloat16(v.x), __float2bfloat16(v.y),
               __float2bfloat16(v.z), __float2bfloat16(v.w)};
  ((us4*)out)[i] = *(const us4*)t;
}

// merged: W1 transpose-cvt | W2 transpose-cvt | text cvt (pad to 1536 rows)
__global__ __launch_bounds__(256) void cvt_wt_k(const float* __restrict__ W1,
                                                const float* __restrict__ W2,
                                                const float* __restrict__ txt,
                                                bf16* __restrict__ W1T,
                                                bf16* __restrict__ W2T,
                                                bf16* __restrict__ Tb) {
  int i = blockIdx.x * 256 + threadIdx.x;
  const int n1 = 3 * 256 * 1024;          // W1T elems
  const int n2 = n1 + 3 * 1024 * 256;     // + W2T elems
  const int n3 = n2 + 1536 * 1024;        // + Tb elems
  if (i < n1) {
    int d = i >> 18, rem = i & 262143;
    int r = rem >> 10, k = rem & 1023;
    W1T[i] = __float2bfloat16(W1[(size_t)d * 262144 + (size_t)k * 256 + r]);
  } else if (i < n2) {
    int j = i - n1;
    int d = j >> 18, rem = j & 262143;
    int n = rem >> 8, k = rem & 255;
    W2T[j] = __float2bfloat16(W2[(size_t)d * 262144 + (size_t)k * 1024 + n]);
  } else if (i < n3) {
    int j = i - n2;
    Tb[j] = (j < 1380 * 1024) ? __float2bfloat16(txt[j]) : __float2bfloat16(0.f);
  }
}

// ---------------- 128^2 2-phase GEMM (verified) for GEMM1/GEMM2 ----------------
template <bool SEG, bool GATHER_A, bool SCATTER_C, bool RELU, bool C_BF16, bool SCALE>
__global__ __launch_bounds__(256) void gemm_bt(
    const bf16* __restrict__ A, const bf16* __restrict__ BT, void* __restrict__ Cv,
    const int* __restrict__ perm, const int* __restrict__ meta, int Mfull, int N,
    int K, int ldc, int Nvalid, const float* __restrict__ scale_ptr) {
  int cnt = Mfull, base = 0;
  if (SEG) {
    int dom = blockIdx.z;
    cnt = meta[dom];
    base = meta[4 + dom];
    BT += (size_t)dom * N * K;
  }
  const int m0 = blockIdx.x * 128;
  if (m0 >= cnt) return;
  const int n0 = blockIdx.y * 128;

  __shared__ bf16 sA[2][128][32];
  __shared__ bf16 sB[2][128][32];

  const int tid = threadIdx.x;
  const int wid = tid >> 6;
  const int lane = tid & 63;

  const int srow = (wid << 4) + (lane >> 2);
  const int skoff = (lane & 3) << 3;

  int p0 = m0 + srow;       if (p0 > cnt - 1) p0 = cnt - 1;
  int p1 = m0 + srow + 64;  if (p1 > cnt - 1) p1 = cnt - 1;
  long ar0, ar1;
  if (GATHER_A) { ar0 = perm[base + p0]; ar1 = perm[base + p1]; }
  else          { ar0 = base + p0;       ar1 = base + p1; }
  const bf16* a0 = A + (size_t)ar0 * K + skoff;
  const bf16* a1 = A + (size_t)ar1 * K + skoff;
  const bf16* b0 = BT + (size_t)(n0 + srow) * K + skoff;
  const bf16* b1 = BT + (size_t)(n0 + srow + 64) * K + skoff;

  const int fr = lane & 15;
  const int fq = lane >> 4;

  f32x4 acc[4][4];
#pragma unroll
  for (int m = 0; m < 4; ++m)
#pragma unroll
    for (int n = 0; n < 4; ++n) acc[m][n] = (f32x4){0.f, 0.f, 0.f, 0.f};

  const int nk = K >> 5;
  auto stage = [&](int buf, int kt) {
    gload_lds16(a0 + kt * 32, &sA[buf][wid * 16][0]);
    gload_lds16(a1 + kt * 32, &sA[buf][wid * 16 + 64][0]);
    gload_lds16(b0 + kt * 32, &sB[buf][wid * 16][0]);
    gload_lds16(b1 + kt * 32, &sB[buf][wid * 16 + 64][0]);
  };

  stage(0, 0);
  __syncthreads();
  const int wr = wid >> 1, wc = wid & 1;
  for (int kt = 0; kt < nk; ++kt) {
    const int cur = kt & 1;
    if (kt + 1 < nk) stage(cur ^ 1, kt + 1);
    bf16x8 af[4], bfr[4];
#pragma unroll
    for (int m = 0; m < 4; ++m)
      af[m] = *(const bf16x8*)&sA[cur][wr * 64 + m * 16 + fr][fq * 8];
#pragma unroll
    for (int n = 0; n < 4; ++n)
      bfr[n] = *(const bf16x8*)&sB[cur][wc * 64 + n * 16 + fr][fq * 8];
#pragma unroll
    for (int m = 0; m < 4; ++m)
#pragma unroll
      for (int n = 0; n < 4; ++n)
        acc[m][n] = __builtin_amdgcn_mfma_f32_16x16x32_bf16(af[m], bfr[n], acc[m][n], 0, 0, 0);
    __syncthreads();
  }

  float s = 1.f;
  if (SCALE) s = expf(*scale_ptr);
#pragma unroll
  for (int m = 0; m < 4; ++m) {
#pragma unroll
    for (int r = 0; r < 4; ++r) {
      const int p = m0 + wr * 64 + m * 16 + fq * 4 + r;
      if (p < cnt) {
        size_t crow;
        if (SCATTER_C) crow = perm[base + p];
        else if (SEG)  crow = base + p;
        else           crow = p;
#pragma unroll
        for (int n = 0; n < 4; ++n) {
          const int col = n0 + wc * 64 + n * 16 + fr;
          if (col < Nvalid) {
            float v = acc[m][n][r];
            if (RELU) v = fmaxf(v, 0.f);
            v *= s;
            if (C_BF16) ((bf16*)Cv)[crow * (size_t)ldc + col] = __float2bfloat16(v);
            else        ((float*)Cv)[crow * (size_t)ldc + col] = v;
          }
        }
      }
    }
  }
}

// ---------------- GEMM3: 256x192 tile, BK=64, 8 waves, counted-vmcnt pipeline ----------------
// C[16384][1380] = exp(ls) * A[16384][1024] @ BT[1536][1024]^T  (BT rows >=1380 zero)
// Grid 64x8 = 512 blocks = exactly 2 full rounds of 256 CUs (packing fix vs R3's 384).
// LDS: A 2x32KB + B 2x24KB = 112KB. Chunk-XOR swizzle both-sides (conflict-free, R3-verified).
// Per K-tile (4 phases): ph1 {rd a0,b0 | stage B(kt+1)u0,u1 | bar | 16 MFMA n01 | bar}
//                        ph2 {          stage B(kt+1)u2    | bar |  8 MFMA n2  | bar}
//                        ph3 {rd a1,b1                     | bar | 16 MFMA n01 | bar}
//                        ph4 {stage A(kt+2)h0,h1 | vmcnt(4)| bar |  8 MFMA n2  | bar}
// vmcnt(4): 11 outstanding -> drains A(kt+1)+B(kt+1) (needed at ph1(kt+1)), keeps A(kt+2).
// Slot-overwrite safe: slot ds_reads all complete by ph3-end barrier.
__global__ __launch_bounds__(512, 2) void gemm3_192(
    const bf16* __restrict__ A, const bf16* __restrict__ BT,
    float* __restrict__ C, const float* __restrict__ scale_ptr) {
  extern __shared__ bf16 smem[];
  bf16* sA0 = smem;            // 2 slots x 16384 bf16
  bf16* sB0 = smem + 32768;    // 2 slots x 12288 bf16

  const int tid = threadIdx.x;
  const int lane = tid & 63, wid = tid >> 6;
  const int wr = wid >> 2, wc = wid & 3;       // 2x4 wave grid; wave C = 128x48
  const int fr = lane & 15, fq = lane >> 4;

  // XCD swizzle: 512 wgs, 512 % 8 == 0 -> bijective; each XCD owns one nb column
  const int bid = blockIdx.x;
  const int wg = (bid & 7) * 64 + (bid >> 3);
  const int mb = wg & 63, nb = wg >> 6;
  const int m0 = mb << 8, n0 = nb * 192;

  auto STAGE_A = [&](int kt, int half) {   // 2 loads/thread
    bf16* dstb = sA0 + ((kt & 1) << 14) + (half << 13);
    const int koff = kt << 6;
#pragma unroll
    for (int L = 0; L < 2; ++L) {
      const int idx = (L << 9) + tid;
      const int r = idx >> 3, c = idx & 7;
      gload_lds16(A + (size_t)(m0 + (half << 7) + r) * 1024 + koff + ((c ^ (r & 7)) << 3),
                  dstb + ((idx & ~63) << 3));
    }
  };
  auto STAGE_B = [&](int kt, int u) {      // u=0..2 (64 rows each), 1 load/thread
    bf16* dstb = sB0 + (kt & 1) * 12288 + (u << 12);
    const int koff = kt << 6;
    const int r = tid >> 3, c = tid & 7;
    gload_lds16(BT + (size_t)(n0 + (u << 6) + r) * 1024 + koff + ((c ^ (r & 7)) << 3),
                dstb + ((tid & ~63) << 3));
  };
  auto LDA = [&](int slot, int kk, bf16x8* dst) {
    const bf16* base = sA0 + (slot << 14);
#pragma unroll
    for (int m = 0; m < 8; ++m) {
      const int row = (wr << 7) + (m << 4) + fr;
      dst[m] = *(const bf16x8*)(base + (row << 6) + ((((kk << 2) + fq) ^ (fr & 7)) << 3));
    }
  };
  auto LDB = [&](int slot, int kk, bf16x8* dst) {
    const bf16* base = sB0 + slot * 12288;
#pragma unroll
    for (int n = 0; n < 3; ++n) {
      const int row = wc * 48 + (n << 4) + fr;
      dst[n] = *(const bf16x8*)(base + (row << 6) + ((((kk << 2) + fq) ^ (fr & 7)) << 3));
    }
  };

  f32x4 acc[8][3];
#pragma unroll
  for (int m = 0; m < 8; ++m)
#pragma unroll
    for (int n = 0; n < 3; ++n) acc[m][n] = (f32x4){0.f, 0.f, 0.f, 0.f};

#define SB __builtin_amdgcn_sched_barrier(0)
#define BAR __builtin_amdgcn_s_barrier()
#define MM2(AF, BF, N0)                                                                   \
  _Pragma("unroll") for (int m = 0; m < 8; ++m) {                                         \
    acc[m][N0]     = __builtin_amdgcn_mfma_f32_16x16x32_bf16(AF[m], BF[N0],     acc[m][N0],     0, 0, 0); \
    acc[m][N0 + 1] = __builtin_amdgcn_mfma_f32_16x16x32_bf16(AF[m], BF[N0 + 1], acc[m][N0 + 1], 0, 0, 0); \
  }
#define MM1(AF, BF, N0)                                                                   \
  _Pragma("unroll") for (int m = 0; m < 8; ++m) {                                         \
    acc[m][N0] = __builtin_amdgcn_mfma_f32_16x16x32_bf16(AF[m], BF[N0], acc[m][N0], 0, 0, 0); \
  }

  // prologue: tile0 (A 4 + B 3 loads) + tile1 A (4); drain tile0, keep A(1) in flight
  STAGE_A(0, 0); STAGE_A(0, 1);
  STAGE_B(0, 0); STAGE_B(0, 1); STAGE_B(0, 2);
  STAGE_A(1, 0); STAGE_A(1, 1);
  asm volatile("s_waitcnt vmcnt(4)" ::: "memory");
  SB; BAR; SB;

  const int nt = 16;
  for (int kt = 0; kt < nt; ++kt) {
    const int slot = kt & 1;
    bf16x8 a0[8], b0[3], a1[8], b1[3];
    // ---- ph1
    LDA(slot, 0, a0); LDB(slot, 0, b0);
    if (kt + 1 < nt) { STAGE_B(kt + 1, 0); STAGE_B(kt + 1, 1); }
    SB; BAR; SB;
    __builtin_amdgcn_s_setprio(1);
    MM2(a0, b0, 0);
    __builtin_amdgcn_s_setprio(0);
    SB; BAR; SB;
    // ---- ph2
    if (kt + 1 < nt) STAGE_B(kt + 1, 2);
    SB; BAR; SB;
    __builtin_amdgcn_s_setprio(1);
    MM1(a0, b0, 2);
    __builtin_amdgcn_s_setprio(0);
    SB; BAR; SB;
    // ---- ph3
    LDA(slot, 1, a1); LDB(slot, 1, b1);
    SB; BAR; SB;
    __builtin_amdgcn_s_setprio(1);
    MM2(a1, b1, 0);
    __builtin_amdgcn_s_setprio(0);
    SB; BAR; SB;
    // ---- ph4
    if (kt + 2 < nt) {
      STAGE_A(kt + 2, 0); STAGE_A(kt + 2, 1);
      asm volatile("s_waitcnt vmcnt(4)" ::: "memory");
    } else if (kt + 1 < nt) {
      asm volatile("s_waitcnt vmcnt(0)" ::: "memory");
    }
    SB; BAR; SB;
    __builtin_amdgcn_s_setprio(1);
    MM1(a1, b1, 2);
    __builtin_amdgcn_s_setprio(0);
    SB; BAR; SB;
  }
#undef MM2
#undef MM1
#undef BAR
#undef SB

  const float sc = expf(*scale_ptr);
#pragma unroll
  for (int m = 0; m < 8; ++m) {
    const int grow = m0 + (wr << 7) + (m << 4) + (fq << 2);
#pragma unroll
    for (int r = 0; r < 4; ++r) {
#pragma unroll
      for (int n = 0; n < 3; ++n) {
        const int gcol = n0 + wc * 48 + (n << 4) + fr;
        if (gcol < 1380) C[(size_t)(grow + r) * 1380 + gcol] = acc[m][n][r] * sc;
      }
    }
  }
}

// ---------------- fused = normalize(0.2*a + 0.8*x), in place over a (bf16) ----------------
__global__ __launch_bounds__(256) void fuse_norm_k(const float* __restrict__ x,
                                                   bf16* __restrict__ F) {
  const int row = blockIdx.x;
  const int t = threadIdx.x;
  const size_t roff = (size_t)row * 1024;
  float f[4];
  float ss = 0.f;
#pragma unroll
  for (int j = 0; j < 4; ++j) {
    const int c = t + j * 256;
    float a = __bfloat162float(F[roff + c]);
    float xv = x[roff + c];
    f[j] = 0.2f * a + 0.8f * xv;
    ss += f[j] * f[j];
  }
#pragma unroll
  for (int o = 32; o > 0; o >>= 1) ss += __shfl_down(ss, o);
  __shared__ float sred[4];
  if ((t & 63) == 0) sred[t >> 6] = ss;
  __syncthreads();
  const float rinv = 1.0f / sqrtf(sred[0] + sred[1] + sred[2] + sred[3]);
#pragma unroll
  for (int j = 0; j < 4; ++j) {
    const int c = t + j * 256;
    F[roff + c] = __float2bfloat16(f[j] * rinv);
  }
}

extern "C" void kernel_launch(void* const* d_in, const int* in_sizes, int n_in,
                              void* d_out, int out_size, void* d_ws, size_t ws_size,
                              hipStream_t stream) {
  (void)in_sizes; (void)n_in; (void)out_size; (void)ws_size;
  const float* x    = (const float*)d_in[0];
  const int*   lab  = (const int*)d_in[1];
  const float* W1   = (const float*)d_in[2];
  const float* W2   = (const float*)d_in[3];
  const float* text = (const float*)d_in[4];
  const float* lsc  = (const float*)d_in[5];
  float* out = (float*)d_out;

  const int B = 16384, D = 1024, R = 256, NTP = 1536;

  char* p = (char*)d_ws;
  auto carve = [&](size_t bytes) {
    char* r = p;
    p += (bytes + 255) & ~(size_t)255;
    return r;
  };
  int*  meta  = (int*)carve(64);
  int*  bhist = (int*)carve(64 * 3 * 4);
  int*  boff  = (int*)carve(64 * 3 * 4);
  int*  perm  = (int*)carve((size_t)B * 4);
  bf16* Xb    = (bf16*)carve((size_t)B * D * 2);     // reused as Fb after GEMM1
  bf16* W1T   = (bf16*)carve((size_t)3 * R * D * 2);
  bf16* W2T   = (bf16*)carve((size_t)3 * D * R * 2);
  bf16* Tb    = (bf16*)carve((size_t)NTP * D * 2);
  bf16* H     = (bf16*)carve((size_t)B * R * 2);
  bf16* Fb    = Xb;

  hist_k<<<B / 256, 256, 0, stream>>>(lab, bhist);
  scan_k<<<1, 256, 0, stream>>>(bhist, boff, meta);
  scatter2_k<<<B / 256, 256, 0, stream>>>(lab, boff, perm);

  cvt_bf16_k<<<(B * D / 4 + 255) / 256, 256, 0, stream>>>(x, Xb, B * D / 4);
  {
    const int total = 3 * R * D + 3 * D * R + NTP * D;
    cvt_wt_k<<<(total + 255) / 256, 256, 0, stream>>>(W1, W2, text, W1T, W2T, Tb);
  }

  // GEMM1: H = relu(Xb[perm] @ W1T[dom]^T)   M=cnt N=256 K=1024
  dim3 g1(128, 2, 3);
  gemm_bt<true, true, false, true, true, false><<<g1, 256, 0, stream>>>(
      Xb, W1T, H, perm, meta, B, R, D, R, R, nullptr);
  // GEMM2: Fb[orig] = relu(H @ W2T[dom]^T)   M=cnt N=1024 K=256 (scatter)
  dim3 g2(128, 8, 3);
  gemm_bt<true, false, true, true, true, false><<<g2, 256, 0, stream>>>(
      H, W2T, Fb, perm, meta, B, D, R, D, D, nullptr);
  fuse_norm_k<<<B, 256, 0, stream>>>(x, Fb);
  // GEMM3: out = exp(ls) * Fb @ Tb^T   M=16384 N=1536(valid 1380) K=1024
  gemm3_192<<<512, 512, 114688, stream>>>(Fb, Tb, out, lsc);
}

// Round 5
// 186.395 us; speedup vs baseline: 1.0474x; 1.0133x over previous
//
#include <hip/hip_runtime.h>
#include <hip/hip_bf16.h>
#include <math.h>

using bf16 = __hip_bfloat16;
typedef __attribute__((ext_vector_type(8))) short bf16x8;   // MFMA A/B frag
typedef __attribute__((ext_vector_type(4))) float f32x4;    // MFMA C/D frag
typedef __attribute__((ext_vector_type(4))) unsigned short us4;

#define GAS __attribute__((address_space(1)))
#define LAS __attribute__((address_space(3)))

__device__ __forceinline__ void gload_lds16(const bf16* g, bf16* lds) {
  __builtin_amdgcn_global_load_lds((const GAS void*)g, (LAS void*)lds, 16, 0, 0);
}
__device__ __forceinline__ float b2f(unsigned short u) {
  union { unsigned short s; bf16 b; } x; x.s = u; return __bfloat162float(x.b);
}
__device__ __forceinline__ unsigned short f2b(float f) {
  union { unsigned short s; bf16 b; } x; x.b = __float2bfloat16(f); return x.s;
}

// ---------------- compaction (atomic-free, stable => deterministic) ----------------
__global__ __launch_bounds__(256) void hist_k(const int* __restrict__ lab,
                                              int* __restrict__ blockHist) {
  const int blk = blockIdx.x, t = threadIdx.x;
  const int lane = t & 63, w = t >> 6;
  const int d = lab[blk * 256 + t];
  __shared__ int wc[4][3];
#pragma unroll
  for (int dd = 0; dd < 3; ++dd) {
    unsigned long long m = __ballot(d == dd);
    if (lane == 0) wc[w][dd] = __popcll(m);
  }
  __syncthreads();
  if (t < 3) blockHist[blk * 3 + t] = wc[0][t] + wc[1][t] + wc[2][t] + wc[3][t];
}

__global__ __launch_bounds__(256) void scan_k(const int* __restrict__ blockHist,
                                              int* __restrict__ blockOff,
                                              int* __restrict__ meta) {
  __shared__ int h[64][3];
  __shared__ int tot[3];
  const int t = threadIdx.x;
  if (t < 192) h[t / 3][t % 3] = blockHist[t];
  __syncthreads();
  if (t < 3) {
    int s = 0;
    for (int b = 0; b < 64; ++b) { int v = h[b][t]; h[b][t] = s; s += v; }
    tot[t] = s;
    meta[t] = s;
  }
  __syncthreads();
  if (t == 0) { meta[4] = 0; meta[5] = tot[0]; meta[6] = tot[0] + tot[1]; }
  if (t < 192) {
    int b = t / 3, d = t % 3;
    int base = (d == 0) ? 0 : (d == 1 ? tot[0] : tot[0] + tot[1]);
    blockOff[t] = base + h[b][d];
  }
}

__global__ __launch_bounds__(256) void scatter2_k(const int* __restrict__ lab,
                                                  const int* __restrict__ blockOff,
                                                  int* __restrict__ perm) {
  const int blk = blockIdx.x, t = threadIdx.x;
  const int lane = t & 63, w = t >> 6;
  const int i = blk * 256 + t;
  const int d = lab[i];
  __shared__ int wc[4][3];
  unsigned long long mymask = 0;
#pragma unroll
  for (int dd = 0; dd < 3; ++dd) {
    unsigned long long m = __ballot(d == dd);
    if (lane == 0) wc[w][dd] = __popcll(m);
    if (dd == d) mymask = m;
  }
  __syncthreads();
  int woff = 0;
  for (int ww = 0; ww < w; ++ww) woff += wc[ww][d];
  const unsigned long long lt = ((unsigned long long)1 << lane) - 1;
  const int rank = blockOff[blk * 3 + d] + woff + __popcll(mymask & lt);
  perm[rank] = i;
}

// ---------------- dtype conversions ----------------
__global__ __launch_bounds__(256) void cvt_bf16_k(const float* __restrict__ in,
                                                  bf16* __restrict__ out, int n4) {
  int i = blockIdx.x * 256 + threadIdx.x;
  if (i >= n4) return;
  float4 v = ((const float4*)in)[i];
  bf16 t[4] = {__float2bfloat16(v.x), __float2bfloat16(v.y),
               __float2bfloat16(v.z), __float2bfloat16(v.w)};
  ((us4*)out)[i] = *(const us4*)t;
}

// merged: W1 transpose-cvt | W2 transpose-cvt | text cvt (pad to 1536 rows)
__global__ __launch_bounds__(256) void cvt_wt_k(const float* __restrict__ W1,
                                                const float* __restrict__ W2,
                                                const float* __restrict__ txt,
                                                bf16* __restrict__ W1T,
                                                bf16* __restrict__ W2T,
                                                bf16* __restrict__ Tb) {
  int i = blockIdx.x * 256 + threadIdx.x;
  const int n1 = 3 * 256 * 1024;
  const int n2 = n1 + 3 * 1024 * 256;
  const int n3 = n2 + 1536 * 1024;
  if (i < n1) {
    int d = i >> 18, rem = i & 262143;
    int r = rem >> 10, k = rem & 1023;
    W1T[i] = __float2bfloat16(W1[(size_t)d * 262144 + (size_t)k * 256 + r]);
  } else if (i < n2) {
    int j = i - n1;
    int d = j >> 18, rem = j & 262143;
    int n = rem >> 8, k = rem & 255;
    W2T[j] = __float2bfloat16(W2[(size_t)d * 262144 + (size_t)k * 1024 + n]);
  } else if (i < n3) {
    int j = i - n2;
    Tb[j] = (j < 1380 * 1024) ? __float2bfloat16(txt[j]) : __float2bfloat16(0.f);
  }
}

// ---------------- 128^2 2-phase GEMM (verified) for GEMM1/GEMM2 ----------------
template <bool SEG, bool GATHER_A, bool SCATTER_C, bool RELU, bool C_BF16, bool SCALE>
__global__ __launch_bounds__(256) void gemm_bt(
    const bf16* __restrict__ A, const bf16* __restrict__ BT, void* __restrict__ Cv,
    const int* __restrict__ perm, const int* __restrict__ meta, int Mfull, int N,
    int K, int ldc, int Nvalid, const float* __restrict__ scale_ptr) {
  int cnt = Mfull, base = 0;
  if (SEG) {
    int dom = blockIdx.z;
    cnt = meta[dom];
    base = meta[4 + dom];
    BT += (size_t)dom * N * K;
  }
  const int m0 = blockIdx.x * 128;
  if (m0 >= cnt) return;
  const int n0 = blockIdx.y * 128;

  __shared__ bf16 sA[2][128][32];
  __shared__ bf16 sB[2][128][32];

  const int tid = threadIdx.x;
  const int wid = tid >> 6;
  const int lane = tid & 63;

  const int srow = (wid << 4) + (lane >> 2);
  const int skoff = (lane & 3) << 3;

  int p0 = m0 + srow;       if (p0 > cnt - 1) p0 = cnt - 1;
  int p1 = m0 + srow + 64;  if (p1 > cnt - 1) p1 = cnt - 1;
  long ar0, ar1;
  if (GATHER_A) { ar0 = perm[base + p0]; ar1 = perm[base + p1]; }
  else          { ar0 = base + p0;       ar1 = base + p1; }
  const bf16* a0 = A + (size_t)ar0 * K + skoff;
  const bf16* a1 = A + (size_t)ar1 * K + skoff;
  const bf16* b0 = BT + (size_t)(n0 + srow) * K + skoff;
  const bf16* b1 = BT + (size_t)(n0 + srow + 64) * K + skoff;

  const int fr = lane & 15;
  const int fq = lane >> 4;

  f32x4 acc[4][4];
#pragma unroll
  for (int m = 0; m < 4; ++m)
#pragma unroll
    for (int n = 0; n < 4; ++n) acc[m][n] = (f32x4){0.f, 0.f, 0.f, 0.f};

  const int nk = K >> 5;
  auto stage = [&](int buf, int kt) {
    gload_lds16(a0 + kt * 32, &sA[buf][wid * 16][0]);
    gload_lds16(a1 + kt * 32, &sA[buf][wid * 16 + 64][0]);
    gload_lds16(b0 + kt * 32, &sB[buf][wid * 16][0]);
    gload_lds16(b1 + kt * 32, &sB[buf][wid * 16 + 64][0]);
  };

  stage(0, 0);
  __syncthreads();
  const int wr = wid >> 1, wc = wid & 1;
  for (int kt = 0; kt < nk; ++kt) {
    const int cur = kt & 1;
    if (kt + 1 < nk) stage(cur ^ 1, kt + 1);
    bf16x8 af[4], bfr[4];
#pragma unroll
    for (int m = 0; m < 4; ++m)
      af[m] = *(const bf16x8*)&sA[cur][wr * 64 + m * 16 + fr][fq * 8];
#pragma unroll
    for (int n = 0; n < 4; ++n)
      bfr[n] = *(const bf16x8*)&sB[cur][wc * 64 + n * 16 + fr][fq * 8];
#pragma unroll
    for (int m = 0; m < 4; ++m)
#pragma unroll
      for (int n = 0; n < 4; ++n)
        acc[m][n] = __builtin_amdgcn_mfma_f32_16x16x32_bf16(af[m], bfr[n], acc[m][n], 0, 0, 0);
    __syncthreads();
  }

  float s = 1.f;
  if (SCALE) s = expf(*scale_ptr);
#pragma unroll
  for (int m = 0; m < 4; ++m) {
#pragma unroll
    for (int r = 0; r < 4; ++r) {
      const int p = m0 + wr * 64 + m * 16 + fq * 4 + r;
      if (p < cnt) {
        size_t crow;
        if (SCATTER_C) crow = perm[base + p];
        else if (SEG)  crow = base + p;
        else           crow = p;
#pragma unroll
        for (int n = 0; n < 4; ++n) {
          const int col = n0 + wc * 64 + n * 16 + fr;
          if (col < Nvalid) {
            float v = acc[m][n][r];
            if (RELU) v = fmaxf(v, 0.f);
            v *= s;
            if (C_BF16) ((bf16*)Cv)[crow * (size_t)ldc + col] = __float2bfloat16(v);
            else        ((float*)Cv)[crow * (size_t)ldc + col] = v;
          }
        }
      }
    }
  }
}

// ---------------- GEMM3 v2: 256x192 tile, BK=64, 8 waves 4x2 (wave 64x96) ----------------
// Per K-tile t (slot s=t&1), 4 phases x 12 MFMA:
//  ph0: rd a0(kk0)x4 + b0(kk0)x6          | bar | MFMA a0 x b0[0..2] | bar
//  ph1: rd a1(kk1)x4 + b1(kk1)x6          | bar | MFMA a0 x b0[3..5] | bar
//  ph2: stage B(t+2) -> slot s (3 loads)  | bar | MFMA a1 x b1[0..2] | bar
//  ph3: stage A(t+2) -> slot s (4 loads); vmcnt(7) | bar | MFMA a1 x b1[3..5] | bar
// All slot-s ds_reads issued by ph1 => ph2/ph3 may overwrite slot s with tile t+2.
// vmcnt(7): FIFO=[tile(t+1) x7 (issued during t-1, ~4 phases old), tile(t+2) x7 young]
// -> drains only the OLD loads; nothing young is ever waited on (fix for R4 stall).
// No sched_barrier(0) (m141); plain s_barrier + setprio(1) around MFMA clusters.
__global__ __launch_bounds__(512, 2) void gemm3_v2(
    const bf16* __restrict__ A, const bf16* __restrict__ BT,
    float* __restrict__ C, const float* __restrict__ scale_ptr) {
  extern __shared__ bf16 smem[];
  bf16* sA0 = smem;            // 2 slots x 16384 bf16 (256 rows x 64)
  bf16* sB0 = smem + 32768;    // 2 slots x 12288 bf16 (192 rows x 64)

  const int tid = threadIdx.x;
  const int lane = tid & 63, wid = tid >> 6;
  const int wr = wid & 3, wc = wid >> 2;       // 4x2 wave grid; wave C = 64 x 96
  const int fr = lane & 15, fq = lane >> 4;

  // XCD swizzle: 512 wgs, bijective; each XCD owns one nb column (B panel L2-resident)
  const int bid = blockIdx.x;
  const int wg = (bid & 7) * 64 + (bid >> 3);
  const int mb = wg & 63, nb = wg >> 6;
  const int m0 = mb << 8, n0 = nb * 192;

  auto STAGE_A = [&](int t, int half) {   // 2 loads/thread
    bf16* dstb = sA0 + ((t & 1) << 14) + (half << 13);
    const int koff = t << 6;
#pragma unroll
    for (int L = 0; L < 2; ++L) {
      const int idx = (L << 9) + tid;
      const int r = idx >> 3, c = idx & 7;
      gload_lds16(A + (size_t)(m0 + (half << 7) + r) * 1024 + koff + ((c ^ (r & 7)) << 3),
                  dstb + ((idx & ~63) << 3));
    }
  };
  auto STAGE_B = [&](int t, int u) {      // u=0..2 (64 rows each), 1 load/thread
    bf16* dstb = sB0 + (t & 1) * 12288 + (u << 12);
    const int koff = t << 6;
    const int r = tid >> 3, c = tid & 7;
    gload_lds16(BT + (size_t)(n0 + (u << 6) + r) * 1024 + koff + ((c ^ (r & 7)) << 3),
                dstb + ((tid & ~63) << 3));
  };
  auto LDA = [&](int slot, int kk, bf16x8* dst) {
    const bf16* base = sA0 + (slot << 14);
#pragma unroll
    for (int m = 0; m < 4; ++m) {
      const int row = (wr << 6) + (m << 4) + fr;
      dst[m] = *(const bf16x8*)(base + (row << 6) + ((((kk << 2) + fq) ^ (fr & 7)) << 3));
    }
  };
  auto LDB = [&](int slot, int kk, bf16x8* dst) {
    const bf16* base = sB0 + slot * 12288;
#pragma unroll
    for (int n = 0; n < 6; ++n) {
      const int row = wc * 96 + (n << 4) + fr;
      dst[n] = *(const bf16x8*)(base + (row << 6) + ((((kk << 2) + fq) ^ (fr & 7)) << 3));
    }
  };

  f32x4 acc[4][6];
#pragma unroll
  for (int m = 0; m < 4; ++m)
#pragma unroll
    for (int n = 0; n < 6; ++n) acc[m][n] = (f32x4){0.f, 0.f, 0.f, 0.f};

#define BAR __builtin_amdgcn_s_barrier()
#define MMH(AF, BF, NB)                                                        \
  _Pragma("unroll") for (int m = 0; m < 4; ++m) {                              \
    _Pragma("unroll") for (int n = 0; n < 3; ++n) {                            \
      acc[m][NB + n] = __builtin_amdgcn_mfma_f32_16x16x32_bf16(                \
          AF[m], BF[NB + n], acc[m][NB + n], 0, 0, 0);                         \
    }                                                                          \
  }

  // prologue: tiles 0 and 1 fully staged; drain tile0, keep tile1 in flight
  STAGE_B(0, 0); STAGE_B(0, 1); STAGE_B(0, 2); STAGE_A(0, 0); STAGE_A(0, 1);
  STAGE_B(1, 0); STAGE_B(1, 1); STAGE_B(1, 2); STAGE_A(1, 0); STAGE_A(1, 1);
  asm volatile("s_waitcnt vmcnt(7)" ::: "memory");
  BAR;

  const int nt = 16;
  for (int t = 0; t < nt; ++t) {
    const int slot = t & 1;
    bf16x8 a0[4], b0[6], a1[4], b1[6];
    // ---- ph0
    LDA(slot, 0, a0); LDB(slot, 0, b0);
    BAR;
    __builtin_amdgcn_s_setprio(1);
    MMH(a0, b0, 0);
    __builtin_amdgcn_s_setprio(0);
    BAR;
    // ---- ph1
    LDA(slot, 1, a1); LDB(slot, 1, b1);
    BAR;
    __builtin_amdgcn_s_setprio(1);
    MMH(a0, b0, 3);
    __builtin_amdgcn_s_setprio(0);
    BAR;
    // ---- ph2
    if (t + 2 < nt) { STAGE_B(t + 2, 0); STAGE_B(t + 2, 1); STAGE_B(t + 2, 2); }
    BAR;
    __builtin_amdgcn_s_setprio(1);
    MMH(a1, b1, 0);
    __builtin_amdgcn_s_setprio(0);
    BAR;
    // ---- ph3
    if (t + 2 < nt) {
      STAGE_A(t + 2, 0); STAGE_A(t + 2, 1);
      asm volatile("s_waitcnt vmcnt(7)" ::: "memory");
    } else if (t + 1 < nt) {
      asm volatile("s_waitcnt vmcnt(0)" ::: "memory");
    }
    BAR;
    __builtin_amdgcn_s_setprio(1);
    MMH(a1, b1, 3);
    __builtin_amdgcn_s_setprio(0);
    BAR;
  }
#undef MMH
#undef BAR

  const float sc = expf(*scale_ptr);
#pragma unroll
  for (int m = 0; m < 4; ++m) {
    const int grow = m0 + (wr << 6) + (m << 4) + (fq << 2);
#pragma unroll
    for (int r = 0; r < 4; ++r) {
#pragma unroll
      for (int n = 0; n < 6; ++n) {
        const int gcol = n0 + wc * 96 + (n << 4) + fr;
        if (gcol < 1380) C[(size_t)(grow + r) * 1380 + gcol] = acc[m][n][r] * sc;
      }
    }
  }
}

// ------- fused = normalize(0.2*a + 0.8*x), in place over F; vectorized loads -------
template <bool XB>
__global__ __launch_bounds__(256) void fuse_norm_k(const float* __restrict__ x,
                                                   const bf16* __restrict__ xb,
                                                   bf16* __restrict__ F) {
  const int row = blockIdx.x;
  const int t = threadIdx.x;
  const size_t roff = (size_t)row * 1024;
  us4 av = ((const us4*)(F + roff))[t];
  float xv[4];
  if (XB) {
    us4 xq = ((const us4*)(xb + roff))[t];
#pragma unroll
    for (int j = 0; j < 4; ++j) xv[j] = b2f(xq[j]);
  } else {
    float4 xf = ((const float4*)(x + roff))[t];
    xv[0] = xf.x; xv[1] = xf.y; xv[2] = xf.z; xv[3] = xf.w;
  }
  float f[4];
  float ss = 0.f;
#pragma unroll
  for (int j = 0; j < 4; ++j) {
    f[j] = 0.2f * b2f(av[j]) + 0.8f * xv[j];
    ss += f[j] * f[j];
  }
#pragma unroll
  for (int o = 32; o > 0; o >>= 1) ss += __shfl_down(ss, o);
  __shared__ float sred[4];
  if ((t & 63) == 0) sred[t >> 6] = ss;
  __syncthreads();
  const float rinv = 1.0f / sqrtf(sred[0] + sred[1] + sred[2] + sred[3]);
  us4 ov;
#pragma unroll
  for (int j = 0; j < 4; ++j) ov[j] = f2b(f[j] * rinv);
  ((us4*)(F + roff))[t] = ov;
}

extern "C" void kernel_launch(void* const* d_in, const int* in_sizes, int n_in,
                              void* d_out, int out_size, void* d_ws, size_t ws_size,
                              hipStream_t stream) {
  (void)in_sizes; (void)n_in; (void)out_size;
  const float* x    = (const float*)d_in[0];
  const int*   lab  = (const int*)d_in[1];
  const float* W1   = (const float*)d_in[2];
  const float* W2   = (const float*)d_in[3];
  const float* text = (const float*)d_in[4];
  const float* lsc  = (const float*)d_in[5];
  float* out = (float*)d_out;

  const int B = 16384, D = 1024, R = 256, NTP = 1536;

  char* p = (char*)d_ws;
  auto carve = [&](size_t bytes) {
    char* r = p;
    p += (bytes + 255) & ~(size_t)255;
    return r;
  };
  int*  meta  = (int*)carve(64);
  int*  bhist = (int*)carve(64 * 3 * 4);
  int*  boff  = (int*)carve(64 * 3 * 4);
  int*  perm  = (int*)carve((size_t)B * 4);
  bf16* Xb    = (bf16*)carve((size_t)B * D * 2);
  bf16* W1T   = (bf16*)carve((size_t)3 * R * D * 2);
  bf16* W2T   = (bf16*)carve((size_t)3 * D * R * 2);
  bf16* Tb    = (bf16*)carve((size_t)NTP * D * 2);
  bf16* H     = (bf16*)carve((size_t)B * R * 2);
  bf16* Fb    = (bf16*)carve((size_t)B * D * 2);    // separate if ws allows
  const bool bigws = (size_t)(p - (char*)d_ws) <= ws_size;
  if (!bigws) Fb = Xb;   // fall back to aliasing (R4 behavior)

  hist_k<<<B / 256, 256, 0, stream>>>(lab, bhist);
  scan_k<<<1, 256, 0, stream>>>(bhist, boff, meta);
  scatter2_k<<<B / 256, 256, 0, stream>>>(lab, boff, perm);

  cvt_bf16_k<<<(B * D / 4 + 255) / 256, 256, 0, stream>>>(x, Xb, B * D / 4);
  {
    const int total = 3 * R * D + 3 * D * R + NTP * D;
    cvt_wt_k<<<(total + 255) / 256, 256, 0, stream>>>(W1, W2, text, W1T, W2T, Tb);
  }

  // GEMM1: H = relu(Xb[perm] @ W1T[dom]^T)   M=cnt N=256 K=1024
  dim3 g1(128, 2, 3);
  gemm_bt<true, true, false, true, true, false><<<g1, 256, 0, stream>>>(
      Xb, W1T, H, perm, meta, B, R, D, R, R, nullptr);
  // GEMM2: Fb[orig] = relu(H @ W2T[dom]^T)   M=cnt N=1024 K=256 (scatter)
  dim3 g2(128, 8, 3);
  gemm_bt<true, false, true, true, true, false><<<g2, 256, 0, stream>>>(
      H, W2T, Fb, perm, meta, B, D, R, D, D, nullptr);
  if (bigws) fuse_norm_k<true><<<B, 256, 0, stream>>>(x, Xb, Fb);
  else       fuse_norm_k<false><<<B, 256, 0, stream>>>(x, nullptr, Fb);
  // GEMM3: out = exp(ls) * Fb @ Tb^T   M=16384 N=1536(valid 1380) K=1024
  gemm3_v2<<<512, 512, 114688, stream>>>(Fb, Tb, out, lsc);
}